// Round 2
// baseline (2106.681 us; speedup 1.0000x reference)
//
#include <hip/hip_runtime.h>
#include <math.h>

#define Bc 8
#define Lc 4096
#define Hc 8
#define Dc 64

// Kernel 1: M[b,h,q] = max_s(Q[q]·K[idx[q,s]]) - (sum_s Q[q]·K[idx[q,s]])/L
// One wave per q (4 waves / block). lane = s for the sampled-key dot products.
__global__ __launch_bounds__(256) void k_meas(
    const float* __restrict__ Q, const float* __restrict__ K,
    const int* __restrict__ idx, float* __restrict__ M, int S)
{
    int b = blockIdx.z, h = blockIdx.y;
    int qq = threadIdx.x >> 6, lane = threadIdx.x & 63;
    int q = blockIdx.x * 4 + qq;

    __shared__ float sQ[4][64];
    sQ[qq][lane] = Q[(((size_t)b * Lc + q) * Hc + h) * Dc + lane];
    __syncthreads();

    float dot = 0.f;
    bool act = lane < S;
    if (act) {
        int kidx = idx[q * S + lane];
        const float4* kr = (const float4*)(K + (((size_t)b * Lc + kidx) * Hc + h) * Dc);
        const float* qrow = sQ[qq];
        #pragma unroll
        for (int i = 0; i < 16; i++) {
            float4 w = kr[i];
            dot += w.x * qrow[4*i] + w.y * qrow[4*i+1]
                 + w.z * qrow[4*i+2] + w.w * qrow[4*i+3];
        }
    }
    float mval = act ? dot : -INFINITY;
    float sval = act ? dot : 0.f;
    #pragma unroll
    for (int o = 32; o >= 1; o >>= 1) {
        mval = fmaxf(mval, __shfl_xor(mval, o, 64));
        sval += __shfl_xor(sval, o, 64);
    }
    if (lane == 0)
        M[((size_t)(b * Hc + h)) * Lc + q] = mval - sval / (float)Lc;
}

// Kernel 2: top-U argmax per (b,h) slice of M (iterative selection in LDS).
__global__ __launch_bounds__(256) void k_topk(
    const float* __restrict__ M, int* __restrict__ top, int U)
{
    int bh = blockIdx.x;
    __shared__ float sM[Lc];
    __shared__ float rv[256];
    __shared__ int   ri[256];
    const float* m = M + (size_t)bh * Lc;
    for (int i = threadIdx.x; i < Lc; i += 256) sM[i] = m[i];
    __syncthreads();

    for (int u = 0; u < U; u++) {
        float bv = -INFINITY; int bi = 0;
        for (int i = threadIdx.x; i < Lc; i += 256) {
            float v = sM[i];
            if (v > bv) { bv = v; bi = i; }
        }
        rv[threadIdx.x] = bv; ri[threadIdx.x] = bi;
        __syncthreads();
        for (int s = 128; s >= 1; s >>= 1) {
            if (threadIdx.x < s) {
                if (rv[threadIdx.x + s] > rv[threadIdx.x]) {
                    rv[threadIdx.x] = rv[threadIdx.x + s];
                    ri[threadIdx.x] = ri[threadIdx.x + s];
                }
            }
            __syncthreads();
        }
        if (threadIdx.x == 0) {
            top[(size_t)bh * U + u] = ri[0];
            sM[ri[0]] = -INFINITY;
        }
        __syncthreads();
    }
}

// Kernel 3: out[b,l,h,d] = cumsum_l V[b,l,h,d]. Chunked scan: 4 chunks of 1024
// rows per (b,h). Each block recomputes its prefix base (reads mostly hit L2).
__global__ __launch_bounds__(256) void k_cumsum(
    const float* __restrict__ V, float* __restrict__ out)
{
    int b = blockIdx.z, h = blockIdx.y, c = blockIdx.x;
    int d = threadIdx.x & 63, g = threadIdx.x >> 6;
    __shared__ float part[4][64];
    __shared__ float gtot[4][64];
    __shared__ float goff[4][64];

    int cstart = c * 1024;
    // Phase A: sum of all rows before this chunk (split over g, stride 4)
    float s = 0.f;
    for (int r = g; r < cstart; r += 4)
        s += V[(((size_t)b * Lc + r) * Hc + h) * Dc + d];
    part[g][d] = s;

    // group sums inside the chunk (256 rows per group)
    int gs = cstart + g * 256;
    float gsum = 0.f;
    for (int r = gs; r < gs + 256; r++)
        gsum += V[(((size_t)b * Lc + r) * Hc + h) * Dc + d];
    gtot[g][d] = gsum;
    __syncthreads();

    if (g == 0) {
        float run = part[0][d] + part[1][d] + part[2][d] + part[3][d];
        for (int gg = 0; gg < 4; gg++) { goff[gg][d] = run; run += gtot[gg][d]; }
    }
    __syncthreads();

    float run = goff[g][d];
    for (int r = gs; r < gs + 256; r++) {
        size_t o = (((size_t)b * Lc + r) * Hc + h) * Dc + d;
        run += V[o];
        out[o] = run;
    }
}

// Kernel 4: for each selected query row: scores = (Q·K^T)/8 over k<=q_idx,
// softmax, attn@V, scatter into out[b,q_idx,h,:]. One block per (b,h,u).
__global__ __launch_bounds__(256) void k_attn(
    const float* __restrict__ Q, const float* __restrict__ K,
    const float* __restrict__ V, const int* __restrict__ top,
    float* __restrict__ out, int U)
{
    int b = blockIdx.z, h = blockIdx.y, u = blockIdx.x;
    int tid = threadIdx.x;
    int q = top[((size_t)(b * Hc + h)) * U + u];
    int n = q + 1;

    __shared__ float sS[Lc];
    __shared__ float sQ[64];
    __shared__ float red[256];

    if (tid < 64)
        sQ[tid] = Q[(((size_t)b * Lc + q) * Hc + h) * Dc + tid] * 0.125f;
    __syncthreads();

    // Pass 1: scores
    for (int k = tid; k < n; k += 256) {
        const float4* kr = (const float4*)(K + (((size_t)b * Lc + k) * Hc + h) * Dc);
        float acc = 0.f;
        #pragma unroll
        for (int i = 0; i < 16; i++) {
            float4 w = kr[i];
            acc += w.x * sQ[4*i] + w.y * sQ[4*i+1]
                 + w.z * sQ[4*i+2] + w.w * sQ[4*i+3];
        }
        sS[k] = acc;
    }
    __syncthreads();

    // max
    float mx = -INFINITY;
    for (int k = tid; k < n; k += 256) mx = fmaxf(mx, sS[k]);
    red[tid] = mx;
    __syncthreads();
    for (int s = 128; s >= 1; s >>= 1) {
        if (tid < s) red[tid] = fmaxf(red[tid], red[tid + s]);
        __syncthreads();
    }
    mx = red[0];
    __syncthreads();

    // exp + sum
    float se = 0.f;
    for (int k = tid; k < n; k += 256) {
        float e = __expf(sS[k] - mx);
        sS[k] = e;
        se += e;
    }
    red[tid] = se;
    __syncthreads();
    for (int s = 128; s >= 1; s >>= 1) {
        if (tid < s) red[tid] += red[tid + s];
        __syncthreads();
    }
    float inv = 1.f / red[0];
    __syncthreads();

    // Pass 2: attn @ V  (thread = (d, key-group g of 4))
    int d = tid & 63, g = tid >> 6;
    float acc = 0.f;
    for (int k = g; k < n; k += 4)
        acc += sS[k] * V[(((size_t)b * Lc + k) * Hc + h) * Dc + d];
    red[g * 64 + d] = acc;
    __syncthreads();
    if (g == 0) {
        float t = (red[d] + red[64 + d] + red[128 + d] + red[192 + d]) * inv;
        out[(((size_t)b * Lc + q) * Hc + h) * Dc + d] = t;
    }
}

extern "C" void kernel_launch(void* const* d_in, const int* in_sizes, int n_in,
                              void* d_out, int out_size, void* d_ws, size_t ws_size,
                              hipStream_t stream)
{
    const float* Q = (const float*)d_in[0];
    const float* K = (const float*)d_in[1];
    const float* V = (const float*)d_in[2];
    const int* idx = (const int*)d_in[3];
    float* out = (float*)d_out;

    int S = in_sizes[3] / Lc;   // sample_k == u == 45

    float* M  = (float*)d_ws;
    int*  top = (int*)((char*)d_ws + (size_t)Bc * Hc * Lc * sizeof(float));

    dim3 blk(256);
    k_meas  <<<dim3(Lc / 4, Hc, Bc), blk, 0, stream>>>(Q, K, idx, M, S);
    k_topk  <<<dim3(Bc * Hc),        blk, 0, stream>>>(M, top, S);
    k_cumsum<<<dim3(Lc / 1024, Hc, Bc), blk, 0, stream>>>(V, out);
    k_attn  <<<dim3(S, Hc, Bc),      blk, 0, stream>>>(Q, K, V, top, out, S);
}

// Round 3
// 954.911 us; speedup vs baseline: 2.2062x; 2.2062x over previous
//
#include <hip/hip_runtime.h>
#include <math.h>

#define Bc 8
#define Lc 4096
#define Hc 8
#define Dc 64
#define CHUNK 512
#define NCH (Lc / CHUNK)   // 8 key-chunks for flash-attn partials
#define VCH 16
#define VROWS (Lc / VCH)   // 256 rows per cumsum chunk

// ---------------------------------------------------------------- kernel 1
// M[b,h,q] = max_s(Q[q]·K[idx[q,s]]) - (sum_s Q[q]·K[idx[q,s]])/L
__global__ __launch_bounds__(256) void k_meas(
    const float* __restrict__ Q, const float* __restrict__ K,
    const int* __restrict__ idx, float* __restrict__ M, int S)
{
    int b = blockIdx.z, h = blockIdx.y;
    int qq = threadIdx.x >> 6, lane = threadIdx.x & 63;
    int q = blockIdx.x * 4 + qq;

    __shared__ float sQ[4][64];
    sQ[qq][lane] = Q[(((size_t)b * Lc + q) * Hc + h) * Dc + lane];
    __syncthreads();

    float dot = 0.f;
    bool act = lane < S;
    if (act) {
        int kidx = idx[q * S + lane];
        const float4* kr = (const float4*)(K + (((size_t)b * Lc + kidx) * Hc + h) * Dc);
        const float* qrow = sQ[qq];
        #pragma unroll
        for (int i = 0; i < 16; i++) {
            float4 w = kr[i];
            dot += w.x * qrow[4*i] + w.y * qrow[4*i+1]
                 + w.z * qrow[4*i+2] + w.w * qrow[4*i+3];
        }
    }
    float mval = act ? dot : -INFINITY;
    float sval = act ? dot : 0.f;
    #pragma unroll
    for (int o = 32; o >= 1; o >>= 1) {
        mval = fmaxf(mval, __shfl_xor(mval, o, 64));
        sval += __shfl_xor(sval, o, 64);
    }
    if (lane == 0)
        M[((size_t)(b * Hc + h)) * Lc + q] = mval - sval / (float)Lc;
}

// ---------------------------------------------------------------- kernel 2
// top-U argmax per (b,h) slice of M (iterative selection in LDS).
__global__ __launch_bounds__(256) void k_topk(
    const float* __restrict__ M, int* __restrict__ top, int U)
{
    int bh = blockIdx.x;
    __shared__ float sM[Lc];
    __shared__ float rv[256];
    __shared__ int   ri[256];
    const float* m = M + (size_t)bh * Lc;
    for (int i = threadIdx.x; i < Lc; i += 256) sM[i] = m[i];
    __syncthreads();

    for (int u = 0; u < U; u++) {
        float bv = -INFINITY; int bi = 0;
        for (int i = threadIdx.x; i < Lc; i += 256) {
            float v = sM[i];
            if (v > bv) { bv = v; bi = i; }
        }
        rv[threadIdx.x] = bv; ri[threadIdx.x] = bi;
        __syncthreads();
        for (int s = 128; s >= 1; s >>= 1) {
            if (threadIdx.x < s) {
                if (rv[threadIdx.x + s] > rv[threadIdx.x]) {
                    rv[threadIdx.x] = rv[threadIdx.x + s];
                    ri[threadIdx.x] = ri[threadIdx.x + s];
                }
            }
            __syncthreads();
        }
        if (threadIdx.x == 0) {
            top[(size_t)bh * U + u] = ri[0];
            sM[ri[0]] = -INFINITY;
        }
        __syncthreads();
    }
}

// ---------------------------------------------------------------- kernel 3a
// per-chunk column sums of V (for the scan's base offsets)
__global__ __launch_bounds__(256) void k_vsum(
    const float* __restrict__ V, float* __restrict__ bsum)
{
    int b = blockIdx.z, h = blockIdx.y, c = blockIdx.x;
    int d = threadIdx.x & 63, g = threadIdx.x >> 6;
    __shared__ float part[4][64];
    float s = 0.f;
    int r0 = c * VROWS;
    for (int r = r0 + g; r < r0 + VROWS; r += 4)
        s += V[(((size_t)b * Lc + r) * Hc + h) * Dc + d];
    part[g][d] = s;
    __syncthreads();
    if (g == 0)
        bsum[(((size_t)(b * Hc + h)) * VCH + c) * 64 + d] =
            part[0][d] + part[1][d] + part[2][d] + part[3][d];
}

// ---------------------------------------------------------------- kernel 3b
// scan within each 256-row chunk, offset by prefix of chunk sums
__global__ __launch_bounds__(256) void k_scan(
    const float* __restrict__ V, const float* __restrict__ bsum,
    float* __restrict__ out)
{
    int b = blockIdx.z, h = blockIdx.y, c = blockIdx.x;
    int d = threadIdx.x & 63, g = threadIdx.x >> 6;
    int bh = b * Hc + h;
    __shared__ float gtot[4][64];
    __shared__ float goff[4][64];

    float base = 0.f;
    for (int cc = 0; cc < c; cc++)
        base += bsum[((size_t)bh * VCH + cc) * 64 + d];

    int gs = c * VROWS + g * 64;
    float gsum = 0.f;
    for (int r = gs; r < gs + 64; r++)
        gsum += V[(((size_t)b * Lc + r) * Hc + h) * Dc + d];
    gtot[g][d] = gsum;
    __syncthreads();
    if (g == 0) {
        float run = base;
        for (int gg = 0; gg < 4; gg++) { goff[gg][d] = run; run += gtot[gg][d]; }
    }
    __syncthreads();
    float run = goff[g][d];
    for (int r = gs; r < gs + 64; r++) {
        size_t o = (((size_t)b * Lc + r) * Hc + h) * Dc + d;
        run += V[o];
        out[o] = run;
    }
}

// ---------------------------------------------------------------- kernel 4
// chunked flash attention over the 45 selected queries per (b,h).
// grid (NCH, H, B); each block handles CHUNK keys for all queries,
// producing per-chunk partials (m, l, unnormalized O).
__global__ __launch_bounds__(256) void k_attn2(
    const float* __restrict__ Q, const float* __restrict__ K,
    const float* __restrict__ V, const int* __restrict__ top,
    float* __restrict__ Opart, float* __restrict__ Mp, float* __restrict__ Lp,
    int U)
{
    int b = blockIdx.z, h = blockIdx.y, c = blockIdx.x;
    int bh = b * Hc + h;
    int tid = threadIdx.x;
    int lane = tid & 63, g = tid >> 6;

    __shared__ float sQ[45][64];     // scaled queries
    __shared__ int   sqi[45];
    __shared__ float sKT[64][65];    // K tile, transposed, padded
    __shared__ float sVT[64][65];    // V tile, transposed, padded
    __shared__ float sP[45][64];     // probs handoff (lane=k -> lane=d)

    if (tid < U) sqi[tid] = top[(size_t)bh * U + tid];
    __syncthreads();
    for (int u = g; u < U; u += 4)
        sQ[u][lane] = Q[(((size_t)b * Lc + sqi[u]) * Hc + h) * Dc + lane] * 0.125f;

    // wave-local query list (wave g owns u = g, g+4, ...)
    int nj = 0, uj[12], qj[12];
    for (int u = g; u < U; u += 4) { uj[nj] = u; qj[nj] = sqi[u]; nj++; }

    float m_r[12], l_r[12], o_r[12];
    #pragma unroll
    for (int j = 0; j < 12; j++) { m_r[j] = -INFINITY; l_r[j] = 0.f; o_r[j] = 0.f; }

    int k0c = c * CHUNK;
    for (int t = 0; t < CHUNK / 64; t++) {
        int k0 = k0c + t * 64;
        __syncthreads();   // previous tile fully consumed
        {   // stage K,V transposed: thread (row=lane, d-group=g)
            const float* kp = K + (((size_t)b * Lc + k0 + lane) * Hc + h) * Dc + g * 16;
            const float* vp = V + (((size_t)b * Lc + k0 + lane) * Hc + h) * Dc + g * 16;
            #pragma unroll
            for (int i = 0; i < 4; i++) {
                float4 kw = *(const float4*)(kp + i * 4);
                float4 vw = *(const float4*)(vp + i * 4);
                int d0 = g * 16 + i * 4;
                sKT[d0+0][lane] = kw.x; sKT[d0+1][lane] = kw.y;
                sKT[d0+2][lane] = kw.z; sKT[d0+3][lane] = kw.w;
                sVT[d0+0][lane] = vw.x; sVT[d0+1][lane] = vw.y;
                sVT[d0+2][lane] = vw.z; sVT[d0+3][lane] = vw.w;
            }
        }
        __syncthreads();

        for (int j = 0; j < nj; j++) {
            int q = qj[j];
            if (k0 > q) continue;      // wave-uniform: tile fully masked
            int u = uj[j];
            // ---- QK^T: lane = key
            float s = 0.f;
            #pragma unroll
            for (int d = 0; d < 64; d += 4) {
                float k0v = sKT[d+0][lane];
                float k1v = sKT[d+1][lane];
                float k2v = sKT[d+2][lane];
                float k3v = sKT[d+3][lane];
                float4 qv = *(const float4*)&sQ[u][d];   // broadcast
                s += qv.x*k0v + qv.y*k1v + qv.z*k2v + qv.w*k3v;
            }
            if (k0 + lane > q) s = -INFINITY;
            // ---- online softmax update
            float tm = s;
            #pragma unroll
            for (int o = 32; o >= 1; o >>= 1) tm = fmaxf(tm, __shfl_xor(tm, o, 64));
            float mnew = fmaxf(m_r[j], tm);              // finite: lane 0 unmasked
            float p = __expf(s - mnew);
            float ps = p;
            #pragma unroll
            for (int o = 32; o >= 1; o >>= 1) ps += __shfl_xor(ps, o, 64);
            float alpha = __expf(m_r[j] - mnew);         // exp(-inf)=0 on first hit
            l_r[j] = l_r[j] * alpha + ps;
            m_r[j] = mnew;
            sP[u][lane] = p;
            // ---- PV: lane = d  (same wave wrote sP row; lgkmcnt orders it)
            float pv = 0.f;
            #pragma unroll
            for (int k = 0; k < 64; k += 4) {
                float v0 = sVT[lane][k+0];
                float v1 = sVT[lane][k+1];
                float v2 = sVT[lane][k+2];
                float v3 = sVT[lane][k+3];
                float4 pw = *(const float4*)&sP[u][k];   // broadcast
                pv += pw.x*v0 + pw.y*v1 + pw.z*v2 + pw.w*v3;
            }
            o_r[j] = o_r[j] * alpha + pv;
        }
    }

    for (int j = 0; j < nj; j++) {
        int u = uj[j];
        size_t s0 = ((size_t)bh * NCH + c) * U + u;
        Opart[s0 * 64 + lane] = o_r[j];
        if (lane == 0) { Mp[s0] = m_r[j]; Lp[s0] = l_r[j]; }
    }
}

// ---------------------------------------------------------------- kernel 5
// merge chunk partials and scatter into the cumsum output rows.
__global__ __launch_bounds__(64) void k_combine(
    const float* __restrict__ Opart, const float* __restrict__ Mp,
    const float* __restrict__ Lp, const int* __restrict__ top,
    float* __restrict__ out, int U)
{
    int b = blockIdx.z, h = blockIdx.y, u = blockIdx.x;
    int bh = b * Hc + h;
    int lane = threadIdx.x;
    int q = top[(size_t)bh * U + u];

    float mv[NCH], lv[NCH];
    float mg = -INFINITY;
    #pragma unroll
    for (int c = 0; c < NCH; c++) {
        size_t s0 = ((size_t)bh * NCH + c) * U + u;
        mv[c] = Mp[s0]; lv[c] = Lp[s0];
        mg = fmaxf(mg, mv[c]);
    }
    float Ls = 0.f, o = 0.f;
    #pragma unroll
    for (int c = 0; c < NCH; c++) {
        if (lv[c] > 0.f) {
            float w = __expf(mv[c] - mg);
            Ls += w * lv[c];
            o  += w * Opart[(((size_t)bh * NCH + c) * U + u) * 64 + lane];
        }
    }
    out[(((size_t)b * Lc + q) * Hc + h) * Dc + lane] = o / Ls;
}

extern "C" void kernel_launch(void* const* d_in, const int* in_sizes, int n_in,
                              void* d_out, int out_size, void* d_ws, size_t ws_size,
                              hipStream_t stream)
{
    const float* Q = (const float*)d_in[0];
    const float* K = (const float*)d_in[1];
    const float* V = (const float*)d_in[2];
    const int* idx = (const int*)d_in[3];
    float* out = (float*)d_out;

    int S = in_sizes[3] / Lc;   // sample_k == u == 45

    // ws layout (bytes). M occupies [0, 8MB) during meas/topk, then is dead;
    // attn partials reuse that region (stream order guarantees safety).
    char* ws = (char*)d_ws;
    float* M     = (float*)ws;                          // 8 MB
    float* Opart = (float*)ws;                          // 5.90 MB (overlaps M)
    float* Mp    = (float*)(ws + 6291456);              // 90 KB
    float* Lp    = (float*)(ws + 6422528);              // 90 KB
    float* bsum  = (float*)(ws + 6815744);              // 256 KB
    int*   top   = (int*)  (ws + 8388608);              // 11.5 KB

    dim3 blk(256);
    k_meas   <<<dim3(Lc / 4, Hc, Bc), blk, 0, stream>>>(Q, K, idx, M, S);
    k_topk   <<<dim3(Bc * Hc),        blk, 0, stream>>>(M, top, S);
    k_vsum   <<<dim3(VCH, Hc, Bc),    blk, 0, stream>>>(V, bsum);
    k_scan   <<<dim3(VCH, Hc, Bc),    blk, 0, stream>>>(V, bsum, out);
    k_attn2  <<<dim3(NCH, Hc, Bc),    blk, 0, stream>>>(Q, K, V, top, Opart, Mp, Lp, S);
    k_combine<<<dim3(S, Hc, Bc), dim3(64), 0, stream>>>(Opart, Mp, Lp, top, out, S);
}

// Round 4
// 767.103 us; speedup vs baseline: 2.7463x; 1.2448x over previous
//
#include <hip/hip_runtime.h>
#include <math.h>

#define Bc 8
#define Lc 4096
#define Hc 8
#define Dc 64
#define CHUNK 512
#define NCH (Lc / CHUNK)   // 8 key-chunks for flash-attn partials
#define VCH 16
#define VROWS (Lc / VCH)   // 256 rows per cumsum chunk

// ---------------------------------------------------------------- kernel 1
// M[b,h,q] = max_s(Q[q]·K[idx[q,s]]) - (sum_s Q[q]·K[idx[q,s]])/L
// Wave = one q. 4 groups of 16 lanes; each group cooperatively loads one
// sampled K row (16 lanes x float4 = 256 B coalesced), 4 rows per wave-iter.
__global__ __launch_bounds__(256) void k_meas(
    const float* __restrict__ Q, const float* __restrict__ K,
    const int* __restrict__ idx, float* __restrict__ M, int S)
{
    int b = blockIdx.z, h = blockIdx.y;
    int w = threadIdx.x >> 6, lane = threadIdx.x & 63;
    int q = blockIdx.x * 4 + w;
    int grp = lane >> 4, gl = lane & 15;

    __shared__ float sQ[4][64];
    __shared__ int   sIdx[4][64];

    sQ[w][lane] = Q[(((size_t)b * Lc + q) * Hc + h) * Dc + lane];
    sIdx[w][lane] = (lane < S) ? idx[q * S + lane] : 0;
    __syncthreads();

    float4 qv = *(const float4*)&sQ[w][gl * 4];

    float mloc = -INFINITY, sloc = 0.f;
    int niter = (S + 3) >> 2;          // 12 for S=45
    for (int it = 0; it < niter; it++) {
        int s = it * 4 + grp;
        int row = sIdx[w][s];
        const float4 kw = *(const float4*)(K + (((size_t)b * Lc + row) * Hc + h) * Dc + gl * 4);
        float d = kw.x * qv.x + kw.y * qv.y + kw.z * qv.z + kw.w * qv.w;
        // reduce within the 16-lane group -> all 16 lanes hold the dot
        d += __shfl_xor(d, 1, 64);
        d += __shfl_xor(d, 2, 64);
        d += __shfl_xor(d, 4, 64);
        d += __shfl_xor(d, 8, 64);
        if (s < S) { mloc = fmaxf(mloc, d); sloc += d; }
    }
    // combine across the 4 groups (lanes within a group are identical,
    // so only group bits 4,5 are xor-combined -> each sample counted once)
    mloc = fmaxf(mloc, __shfl_xor(mloc, 16, 64));
    mloc = fmaxf(mloc, __shfl_xor(mloc, 32, 64));
    sloc += __shfl_xor(sloc, 16, 64);
    sloc += __shfl_xor(sloc, 32, 64);

    if (lane == 0)
        M[((size_t)(b * Hc + h)) * Lc + q] = mloc - sloc / (float)Lc;
}

// ---------------------------------------------------------------- kernel 2
// top-U argmax per (b,h) slice of M (iterative selection in LDS).
__global__ __launch_bounds__(256) void k_topk(
    const float* __restrict__ M, int* __restrict__ top, int U)
{
    int bh = blockIdx.x;
    __shared__ float sM[Lc];
    __shared__ float rv[256];
    __shared__ int   ri[256];
    const float* m = M + (size_t)bh * Lc;
    for (int i = threadIdx.x; i < Lc; i += 256) sM[i] = m[i];
    __syncthreads();

    for (int u = 0; u < U; u++) {
        float bv = -INFINITY; int bi = 0;
        for (int i = threadIdx.x; i < Lc; i += 256) {
            float v = sM[i];
            if (v > bv) { bv = v; bi = i; }
        }
        rv[threadIdx.x] = bv; ri[threadIdx.x] = bi;
        __syncthreads();
        for (int s = 128; s >= 1; s >>= 1) {
            if (threadIdx.x < s) {
                if (rv[threadIdx.x + s] > rv[threadIdx.x]) {
                    rv[threadIdx.x] = rv[threadIdx.x + s];
                    ri[threadIdx.x] = ri[threadIdx.x + s];
                }
            }
            __syncthreads();
        }
        if (threadIdx.x == 0) {
            top[(size_t)bh * U + u] = ri[0];
            sM[ri[0]] = -INFINITY;
        }
        __syncthreads();
    }
}

// ---------------------------------------------------------------- kernel 3a
// per-chunk column sums of V (for the scan's base offsets)
__global__ __launch_bounds__(256) void k_vsum(
    const float* __restrict__ V, float* __restrict__ bsum)
{
    int b = blockIdx.z, h = blockIdx.y, c = blockIdx.x;
    int d = threadIdx.x & 63, g = threadIdx.x >> 6;
    __shared__ float part[4][64];
    float s = 0.f;
    int r0 = c * VROWS;
    for (int r = r0 + g; r < r0 + VROWS; r += 4)
        s += V[(((size_t)b * Lc + r) * Hc + h) * Dc + d];
    part[g][d] = s;
    __syncthreads();
    if (g == 0)
        bsum[(((size_t)(b * Hc + h)) * VCH + c) * 64 + d] =
            part[0][d] + part[1][d] + part[2][d] + part[3][d];
}

// ---------------------------------------------------------------- kernel 3b
// scan within each 256-row chunk, offset by prefix of chunk sums
__global__ __launch_bounds__(256) void k_scan(
    const float* __restrict__ V, const float* __restrict__ bsum,
    float* __restrict__ out)
{
    int b = blockIdx.z, h = blockIdx.y, c = blockIdx.x;
    int d = threadIdx.x & 63, g = threadIdx.x >> 6;
    int bh = b * Hc + h;
    __shared__ float gtot[4][64];
    __shared__ float goff[4][64];

    float base = 0.f;
    for (int cc = 0; cc < c; cc++)
        base += bsum[((size_t)bh * VCH + cc) * 64 + d];

    int gs = c * VROWS + g * 64;
    float gsum = 0.f;
    for (int r = gs; r < gs + 64; r++)
        gsum += V[(((size_t)b * Lc + r) * Hc + h) * Dc + d];
    gtot[g][d] = gsum;
    __syncthreads();
    if (g == 0) {
        float run = base;
        for (int gg = 0; gg < 4; gg++) { goff[gg][d] = run; run += gtot[gg][d]; }
    }
    __syncthreads();
    float run = goff[g][d];
    for (int r = gs; r < gs + 64; r++) {
        size_t o = (((size_t)b * Lc + r) * Hc + h) * Dc + d;
        run += V[o];
        out[o] = run;
    }
}

// ---------------------------------------------------------------- kernel 4
// chunked flash attention over the selected queries per (b,h).
__global__ __launch_bounds__(256) void k_attn2(
    const float* __restrict__ Q, const float* __restrict__ K,
    const float* __restrict__ V, const int* __restrict__ top,
    float* __restrict__ Opart, float* __restrict__ Mp, float* __restrict__ Lp,
    int U)
{
    int b = blockIdx.z, h = blockIdx.y, c = blockIdx.x;
    int bh = b * Hc + h;
    int tid = threadIdx.x;
    int lane = tid & 63, g = tid >> 6;

    __shared__ float sQ[45][64];     // scaled queries
    __shared__ int   sqi[45];
    __shared__ float sKT[64][65];    // K tile, transposed, padded
    __shared__ float sVT[64][65];    // V tile, transposed, padded
    __shared__ float sP[45][64];     // probs handoff (lane=k -> lane=d)

    if (tid < U) sqi[tid] = top[(size_t)bh * U + tid];
    __syncthreads();
    for (int u = g; u < U; u += 4)
        sQ[u][lane] = Q[(((size_t)b * Lc + sqi[u]) * Hc + h) * Dc + lane] * 0.125f;

    // wave-local query list (wave g owns u = g, g+4, ...)
    int nj = 0, uj[12], qj[12];
    for (int u = g; u < U; u += 4) { uj[nj] = u; qj[nj] = sqi[u]; nj++; }

    float m_r[12], l_r[12], o_r[12];
    #pragma unroll
    for (int j = 0; j < 12; j++) { m_r[j] = -INFINITY; l_r[j] = 0.f; o_r[j] = 0.f; }

    int k0c = c * CHUNK;
    for (int t = 0; t < CHUNK / 64; t++) {
        int k0 = k0c + t * 64;
        __syncthreads();   // previous tile fully consumed
        {   // stage K,V transposed: thread (row=lane, d-group=g)
            const float* kp = K + (((size_t)b * Lc + k0 + lane) * Hc + h) * Dc + g * 16;
            const float* vp = V + (((size_t)b * Lc + k0 + lane) * Hc + h) * Dc + g * 16;
            #pragma unroll
            for (int i = 0; i < 4; i++) {
                float4 kw = *(const float4*)(kp + i * 4);
                float4 vw = *(const float4*)(vp + i * 4);
                int d0 = g * 16 + i * 4;
                sKT[d0+0][lane] = kw.x; sKT[d0+1][lane] = kw.y;
                sKT[d0+2][lane] = kw.z; sKT[d0+3][lane] = kw.w;
                sVT[d0+0][lane] = vw.x; sVT[d0+1][lane] = vw.y;
                sVT[d0+2][lane] = vw.z; sVT[d0+3][lane] = vw.w;
            }
        }
        __syncthreads();

        for (int j = 0; j < nj; j++) {
            int q = qj[j];
            if (k0 > q) continue;      // wave-uniform: tile fully masked
            int u = uj[j];
            // ---- QK^T: lane = key
            float s = 0.f;
            #pragma unroll
            for (int d = 0; d < 64; d += 4) {
                float k0v = sKT[d+0][lane];
                float k1v = sKT[d+1][lane];
                float k2v = sKT[d+2][lane];
                float k3v = sKT[d+3][lane];
                float4 qv = *(const float4*)&sQ[u][d];   // broadcast
                s += qv.x*k0v + qv.y*k1v + qv.z*k2v + qv.w*k3v;
            }
            if (k0 + lane > q) s = -INFINITY;
            // ---- online softmax update
            float tm = s;
            #pragma unroll
            for (int o = 32; o >= 1; o >>= 1) tm = fmaxf(tm, __shfl_xor(tm, o, 64));
            float mnew = fmaxf(m_r[j], tm);              // finite: lane 0 unmasked
            float p = __expf(s - mnew);
            float ps = p;
            #pragma unroll
            for (int o = 32; o >= 1; o >>= 1) ps += __shfl_xor(ps, o, 64);
            float alpha = __expf(m_r[j] - mnew);         // exp(-inf)=0 on first hit
            l_r[j] = l_r[j] * alpha + ps;
            m_r[j] = mnew;
            sP[u][lane] = p;
            // ---- PV: lane = d  (same wave wrote sP row; lgkmcnt orders it)
            float pv = 0.f;
            #pragma unroll
            for (int k = 0; k < 64; k += 4) {
                float v0 = sVT[lane][k+0];
                float v1 = sVT[lane][k+1];
                float v2 = sVT[lane][k+2];
                float v3 = sVT[lane][k+3];
                float4 pw = *(const float4*)&sP[u][k];   // broadcast
                pv += pw.x*v0 + pw.y*v1 + pw.z*v2 + pw.w*v3;
            }
            o_r[j] = o_r[j] * alpha + pv;
        }
    }

    for (int j = 0; j < nj; j++) {
        int u = uj[j];
        size_t s0 = ((size_t)bh * NCH + c) * U + u;
        Opart[s0 * 64 + lane] = o_r[j];
        if (lane == 0) { Mp[s0] = m_r[j]; Lp[s0] = l_r[j]; }
    }
}

// ---------------------------------------------------------------- kernel 5
// merge chunk partials and scatter into the cumsum output rows.
__global__ __launch_bounds__(64) void k_combine(
    const float* __restrict__ Opart, const float* __restrict__ Mp,
    const float* __restrict__ Lp, const int* __restrict__ top,
    float* __restrict__ out, int U)
{
    int b = blockIdx.z, h = blockIdx.y, u = blockIdx.x;
    int bh = b * Hc + h;
    int lane = threadIdx.x;
    int q = top[(size_t)bh * U + u];

    float mv[NCH], lv[NCH];
    float mg = -INFINITY;
    #pragma unroll
    for (int c = 0; c < NCH; c++) {
        size_t s0 = ((size_t)bh * NCH + c) * U + u;
        mv[c] = Mp[s0]; lv[c] = Lp[s0];
        mg = fmaxf(mg, mv[c]);
    }
    float Ls = 0.f, o = 0.f;
    #pragma unroll
    for (int c = 0; c < NCH; c++) {
        if (lv[c] > 0.f) {
            float w = __expf(mv[c] - mg);
            Ls += w * lv[c];
            o  += w * Opart[(((size_t)bh * NCH + c) * U + u) * 64 + lane];
        }
    }
    out[(((size_t)b * Lc + q) * Hc + h) * Dc + lane] = o / Ls;
}

extern "C" void kernel_launch(void* const* d_in, const int* in_sizes, int n_in,
                              void* d_out, int out_size, void* d_ws, size_t ws_size,
                              hipStream_t stream)
{
    const float* Q = (const float*)d_in[0];
    const float* K = (const float*)d_in[1];
    const float* V = (const float*)d_in[2];
    const int* idx = (const int*)d_in[3];
    float* out = (float*)d_out;

    int S = in_sizes[3] / Lc;   // sample_k == u == 45

    // ws layout (bytes). M occupies [0, 8MB) during meas/topk, then is dead;
    // attn partials reuse that region (stream order guarantees safety).
    char* ws = (char*)d_ws;
    float* M     = (float*)ws;                          // 8 MB
    float* Opart = (float*)ws;                          // 5.90 MB (overlaps M)
    float* Mp    = (float*)(ws + 6291456);              // 90 KB
    float* Lp    = (float*)(ws + 6422528);              // 90 KB
    float* bsum  = (float*)(ws + 6815744);              // 256 KB
    int*   top   = (int*)  (ws + 8388608);              // 11.5 KB

    dim3 blk(256);
    k_meas   <<<dim3(Lc / 4, Hc, Bc), blk, 0, stream>>>(Q, K, idx, M, S);
    k_topk   <<<dim3(Bc * Hc),        blk, 0, stream>>>(M, top, S);
    k_vsum   <<<dim3(VCH, Hc, Bc),    blk, 0, stream>>>(V, bsum);
    k_scan   <<<dim3(VCH, Hc, Bc),    blk, 0, stream>>>(V, bsum, out);
    k_attn2  <<<dim3(NCH, Hc, Bc),    blk, 0, stream>>>(Q, K, V, top, Opart, Mp, Lp, S);
    k_combine<<<dim3(S, Hc, Bc), dim3(64), 0, stream>>>(Opart, Mp, Lp, top, out, S);
}